// Round 1
// baseline (134.493 us; speedup 1.0000x reference)
//
#include <hip/hip_runtime.h>

#define B 64
#define S 512
#define D 768
#define E 32
#define N_ENT (B * E)        // 2048
#define MPE 4
#define M (N_ENT * MPE)      // 8192
#define N_TYPES 6
#define P (B * E * (E - 1))  // 63488

// ---------------------------------------------------------------------------
// Kernel 1: per-(entity, dim) logsumexp over the entity's MPE=4 mentions.
// mention_entity = arange(M)//MPE  (contiguous groups of 4), verified by
// reading mention_entity[4e] for the doc index instead of assuming e//E.
// ---------------------------------------------------------------------------
__global__ void ent_lse_kernel(const float* __restrict__ hidden,
                               const int* __restrict__ mention_entity,
                               const int* __restrict__ mention_pos,
                               float* __restrict__ ent) {
    int idx = blockIdx.x * blockDim.x + threadIdx.x;  // over N_ENT*D
    if (idx >= N_ENT * D) return;
    int e = idx / D;
    int d = idx - e * D;

    int doc = mention_entity[e * MPE] / E;  // == e / E for this dataset
    const float* base = hidden + (size_t)doc * S * D + d;

    float x[MPE];
#pragma unroll
    for (int m = 0; m < MPE; ++m) {
        int pos = mention_pos[e * MPE + m] + 1;
        x[m] = base[(size_t)pos * D];
    }
    float mx = x[0];
#pragma unroll
    for (int m = 1; m < MPE; ++m) mx = fmaxf(mx, x[m]);
    float s = 0.f;
#pragma unroll
    for (int m = 0; m < MPE; ++m) s += expf(x[m] - mx);
    ent[idx] = logf(s) + mx;
}

// ---------------------------------------------------------------------------
// Kernel 2: one block (192 threads = D/4 float4 slots) per pair.
//   row 0: cls = hidden[doc, 0, :]
//   row 1: ent[pair_head]
//   row 2: ent[pair_tail]
// Lanes 0..5 additionally write pair_types (one-hot(head)+one-hot(tail)).
// All writes are float4 / coalesced; gathers hit L2/L3 (cls 192 KB, ent 6 MB).
// ---------------------------------------------------------------------------
__global__ void pair_feat_kernel(const float* __restrict__ hidden,
                                 const int* __restrict__ pair_head,
                                 const int* __restrict__ pair_tail,
                                 const int* __restrict__ pair_doc,
                                 const int* __restrict__ ent_type,
                                 const float* __restrict__ ent,
                                 float* __restrict__ out_feat,
                                 float* __restrict__ out_types) {
    const int p = blockIdx.x;
    const int t = threadIdx.x;  // 0..191

    const int doc = pair_doc[p];
    const int h  = pair_head[p];
    const int tl = pair_tail[p];

    const float4* cls4 = (const float4*)(hidden + (size_t)doc * S * D);  // row 0 of doc
    const float4* eh4  = (const float4*)(ent + (size_t)h * D);
    const float4* et4  = (const float4*)(ent + (size_t)tl * D);
    float4* o = (float4*)(out_feat + (size_t)p * 3 * D);

    o[t]           = cls4[t];
    o[D / 4 + t]   = eh4[t];
    o[D / 2 + t]   = et4[t];

    if (t < N_TYPES) {
        int th = ent_type[h];
        int tt = ent_type[tl];
        out_types[(size_t)p * N_TYPES + t] =
            (float)((t == th) ? 1 : 0) + (float)((t == tt) ? 1 : 0);
    }
}

extern "C" void kernel_launch(void* const* d_in, const int* in_sizes, int n_in,
                              void* d_out, int out_size, void* d_ws, size_t ws_size,
                              hipStream_t stream) {
    const float* hidden         = (const float*)d_in[0];
    const int* mention_entity   = (const int*)d_in[1];
    const int* mention_pos      = (const int*)d_in[2];
    const int* pair_head        = (const int*)d_in[3];
    const int* pair_tail        = (const int*)d_in[4];
    const int* pair_doc         = (const int*)d_in[5];
    const int* ent_type         = (const int*)d_in[6];

    float* out       = (float*)d_out;
    float* out_feat  = out;                        // P*3*D floats
    float* out_types = out + (size_t)P * 3 * D;    // P*6 floats

    float* ent = (float*)d_ws;                     // N_ENT*D floats = 6.3 MB

    const int total = N_ENT * D;
    ent_lse_kernel<<<(total + 255) / 256, 256, 0, stream>>>(
        hidden, mention_entity, mention_pos, ent);

    pair_feat_kernel<<<P, D / 4, 0, stream>>>(
        hidden, pair_head, pair_tail, pair_doc, ent_type, ent,
        out_feat, out_types);
}

// Round 2
// 104.047 us; speedup vs baseline: 1.2926x; 1.2926x over previous
//
#include <hip/hip_runtime.h>

#define B 64
#define S 512
#define D 768
#define E 32
#define N_ENT (B * E)        // 2048
#define MPE 4
#define M (N_ENT * MPE)      // 8192
#define N_TYPES 6
#define P (B * E * (E - 1))  // 63488

#define D4 (D / 4)                     // 192 float4 slots per row
#define LSE_THREADS (N_ENT * D4)       // 393216
#define LSE_BLOCKS (LSE_THREADS / 256) // 1536
#define TYPES_ELEMS (P * N_TYPES)      // 380928
#define TYPES_BLOCKS ((TYPES_ELEMS + 255) / 256) // 1488
#define FEAT_SLOTS (P * 3 * D4)        // 36,569,088 float4 slots

typedef float f32x4 __attribute__((ext_vector_type(4)));

__device__ __forceinline__ float lse4(float a, float b, float c, float d) {
    float mx = fmaxf(fmaxf(a, b), fmaxf(c, d));
    return logf(expf(a - mx) + expf(b - mx) + expf(c - mx) + expf(d - mx)) + mx;
}

// ---------------------------------------------------------------------------
// Kernel 1 (two independent jobs folded into one dispatch):
//  blocks [0, LSE_BLOCKS): per-(entity, d4) logsumexp over MPE=4 mentions,
//    vectorized float4, writes ent[N_ENT][D] into workspace.
//  blocks [LSE_BLOCKS, ...): pair_types = one_hot(type[h]) + one_hot(type[t]).
// ---------------------------------------------------------------------------
__global__ __launch_bounds__(256) void prep_kernel(
    const float* __restrict__ hidden,
    const int* __restrict__ mention_entity,
    const int* __restrict__ mention_pos,
    const int* __restrict__ pair_head,
    const int* __restrict__ pair_tail,
    const int* __restrict__ ent_type,
    float* __restrict__ ent,
    float* __restrict__ out_types) {
    const unsigned b = blockIdx.x;
    const unsigned t = threadIdx.x;

    if (b < LSE_BLOCKS) {
        const unsigned idx = b * 256u + t;          // over N_ENT * D4
        const unsigned e = idx / D4;
        const unsigned d4 = idx - e * D4;
        const int doc = mention_entity[e * MPE] / E;
        const float* rowbase = hidden + (size_t)doc * S * D + (size_t)d4 * 4;

        f32x4 x[MPE];
#pragma unroll
        for (int m = 0; m < MPE; ++m) {
            const int pos = mention_pos[e * MPE + m] + 1;
            x[m] = *(const f32x4*)(rowbase + (size_t)pos * D);
        }
        f32x4 o;
        o.x = lse4(x[0].x, x[1].x, x[2].x, x[3].x);
        o.y = lse4(x[0].y, x[1].y, x[2].y, x[3].y);
        o.z = lse4(x[0].z, x[1].z, x[2].z, x[3].z);
        o.w = lse4(x[0].w, x[1].w, x[2].w, x[3].w);
        *(f32x4*)(ent + (size_t)e * D + (size_t)d4 * 4) = o;
    } else {
        const unsigned i = (b - LSE_BLOCKS) * 256u + t;  // over P * N_TYPES
        if (i < TYPES_ELEMS) {
            const unsigned p = i / N_TYPES;
            const int ty = (int)(i - p * N_TYPES);
            const int th = ent_type[pair_head[p]];
            const int tt = ent_type[pair_tail[p]];
            out_types[i] = (float)((ty == th) + (ty == tt));
        }
    }
}

// ---------------------------------------------------------------------------
// Kernel 2: flat grid-stride over all P*3*D4 output float4 slots.
// 192 slots/row = exactly 3 waves, and both block size (256) and the grid
// stride (multiples of 64) keep every wave inside one source row -> p and r
// are wave-uniform: non-divergent branch, broadcast index loads, 1KB-coalesced
// reads, perfectly streaming nontemporal stores.
// ---------------------------------------------------------------------------
__global__ __launch_bounds__(256) void feat_kernel(
    const float* __restrict__ hidden,
    const int* __restrict__ pair_head,
    const int* __restrict__ pair_tail,
    const int* __restrict__ pair_doc,
    const float* __restrict__ ent,
    f32x4* __restrict__ out4) {
    const unsigned stride = gridDim.x * blockDim.x;
    for (unsigned idx = blockIdx.x * blockDim.x + threadIdx.x;
         idx < (unsigned)FEAT_SLOTS; idx += stride) {
        const unsigned p = idx / (3 * D4);          // /576 -> magic mul
        const unsigned rem = idx - p * (3 * D4);
        const unsigned r = rem / D4;                // 0,1,2 (wave-uniform)
        const unsigned d4 = rem - r * D4;

        const f32x4* src;
        if (r == 0) {
            src = (const f32x4*)(hidden + (size_t)pair_doc[p] * (S * D));
        } else {
            const int q = (r == 1) ? pair_head[p] : pair_tail[p];
            src = (const f32x4*)(ent + (size_t)q * D);
        }
        __builtin_nontemporal_store(src[d4], &out4[idx]);
    }
}

extern "C" void kernel_launch(void* const* d_in, const int* in_sizes, int n_in,
                              void* d_out, int out_size, void* d_ws, size_t ws_size,
                              hipStream_t stream) {
    const float* hidden       = (const float*)d_in[0];
    const int* mention_entity = (const int*)d_in[1];
    const int* mention_pos    = (const int*)d_in[2];
    const int* pair_head      = (const int*)d_in[3];
    const int* pair_tail      = (const int*)d_in[4];
    const int* pair_doc       = (const int*)d_in[5];
    const int* ent_type       = (const int*)d_in[6];

    float* out       = (float*)d_out;
    float* out_feat  = out;                      // P*3*D floats
    float* out_types = out + (size_t)P * 3 * D;  // P*N_TYPES floats

    float* ent = (float*)d_ws;                   // N_ENT*D floats = 6.3 MB

    prep_kernel<<<LSE_BLOCKS + TYPES_BLOCKS, 256, 0, stream>>>(
        hidden, mention_entity, mention_pos, pair_head, pair_tail, ent_type,
        ent, out_types);

    feat_kernel<<<2048, 256, 0, stream>>>(
        hidden, pair_head, pair_tail, pair_doc, ent, (f32x4*)out_feat);
}